// Round 17
// baseline (415.486 us; speedup 1.0000x reference)
//
#include <hip/hip_runtime.h>
#include <hip/hip_fp16.h>

#define K_DIM 4096
#define N_DIM 11008
#define NZ8   1376          // N_DIM/8
#define BM    256
#define BN    256
#define NT_N  43            // N_DIM/BN
#define NKT   64            // K_DIM/64
#define ATB   32768         // A tile bytes = 256*64*2

typedef _Float16 f16x8  __attribute__((ext_vector_type(8)));
typedef float    f32x16 __attribute__((ext_vector_type(16)));

#define SB()     __builtin_amdgcn_sched_barrier(0)
#define BAR()    __builtin_amdgcn_s_barrier()
#define VMW(N)   do { asm volatile("s_waitcnt vmcnt(" #N ")" ::: "memory"); SB(); } while (0)
#define LGKMC(N) do { asm volatile("s_waitcnt lgkmcnt(" #N ")" ::: "memory"); SB(); } while (0)

// 1 int32 -> 8 fp16 dequant, (k,k+4)-interleaved order (matches ws interleave)
__device__ __forceinline__ f16x8 dq8(unsigned q, __half2 scp, __half2 nzp)
{
    const unsigned mu = 0xE400E400u;
    const __half2 m1024 = *(const __half2*)&mu;
    union { __half2 h2[4]; f16x8 v; } p;
#pragma unroll
    for (int d = 0; d < 4; ++d) {
        unsigned t = ((q >> (4 * d)) & 0x000F000Fu) | 0x64006400u;
        p.h2[d] = __hfma2(__hadd2(*(const __half2*)&t, m1024), scp, nzp);
    }
    return p.v;
}

// ---- pre-pass: x f32 -> fp16 ws, layout [mtile][ktile][chunk(8)][row][16B]
// chunk c holds k = kt*64 + c*8 .. +8 in order (k0,k4,k1,k5,k2,k6,k3,k7).
// (byte-identical layout to r13/r15's [kh][slot][row] — c = kh*4+slot)
__global__ __launch_bounds__(256)
void r17_xcvt(const float* __restrict__ x, __half* __restrict__ xh, int nchunks)
{
    int c = blockIdx.x * 256 + threadIdx.x;
    const int stride = gridDim.x * 256;
    for (; c < nchunks; c += stride) {
        const int row = c & 255;
        const int ch  = (c >> 8) & 7;
        const int tl  = c >> 11;
        const int mt  = tl >> 6;
        const int kt  = tl & 63;
        const size_t gm = (size_t)mt * 256 + row;
        const int kb = kt * 64 + ch * 8;
        const float4 f0 = *(const float4*)(x + gm * K_DIM + kb);
        const float4 f1 = *(const float4*)(x + gm * K_DIM + kb + 4);
        union { __half2 h2[4]; int4 v; } p;
        p.h2[0] = __floats2half2_rn(f0.x, f1.x);
        p.h2[1] = __floats2half2_rn(f0.y, f1.y);
        p.h2[2] = __floats2half2_rn(f0.z, f1.z);
        p.h2[3] = __floats2half2_rn(f0.w, f1.w);
        ((int4*)xh)[c] = p.v;
    }
}

// ---- ledger issue helpers (proven 64-bit-vaddr asm form) ----
// 8 q-dwords/tile: rows kt*8 + {0,2,4,6} + hi, cols colb + {0,32}
#define ISSUE_Q8(D0,D1,D2,D3,D4,D5,D6,D7) do { \
    asm volatile( \
        "global_load_dword %0, %8, off\n\t" \
        "global_load_dword %1, %8, off offset:128\n\t" \
        "global_load_dword %2, %9, off\n\t" \
        "global_load_dword %3, %9, off offset:128\n\t" \
        "global_load_dword %4, %10, off\n\t" \
        "global_load_dword %5, %10, off offset:128\n\t" \
        "global_load_dword %6, %11, off\n\t" \
        "global_load_dword %7, %11, off offset:128" \
        : "=&v"(D0), "=&v"(D1), "=&v"(D2), "=&v"(D3), \
          "=&v"(D4), "=&v"(D5), "=&v"(D6), "=&v"(D7) \
        : "v"(qp0), "v"(qp1), "v"(qp2), "v"(qp3) : "memory"); \
    qp0 += 8 * N_DIM; qp1 += 8 * N_DIM; qp2 += 8 * N_DIM; qp3 += 8 * N_DIM; \
} while (0)

// 2 scales + 2 qzero dwords for the NEXT group (cols colb, colb+32)
#define ISSUE_SZ() do { \
    asm volatile( \
        "global_load_dword %0, %4, off\n\t" \
        "global_load_dword %1, %4, off offset:128\n\t" \
        "global_load_dword %2, %5, off\n\t" \
        "global_load_dword %3, %5, off offset:16" \
        : "=&v"(sS0), "=&v"(sS1), "=&v"(sZ0), "=&v"(sZ1) \
        : "v"(sp), "v"(zp) : "memory"); \
    sp += N_DIM; zp += NZ8; \
} while (0)

#define ISSUE_A(BUFP, T) do { \
    const char* _s = agp + (size_t)(T) * ATB; \
    _Pragma("unroll") for (int j = 0; j < 4; ++j) \
        __builtin_amdgcn_global_load_lds((const unsigned int*)(_s + j * 8192), \
            (unsigned int*)((BUFP) + j * 8192 + tid * 16), 16, 0, 0); \
} while (0)

// 4 A-fragments (one per 32-row mblk) for k-step KS
#define FRAGS_KS(ARp, KS, DEST) do { \
    _Pragma("unroll") for (int mb = 0; mb < 4; ++mb) \
        DEST[mb] = *(const f16x8*)((ARp) + (KS) * 8192 + aBase + mb * 512); \
} while (0)

#define DQ2(Q0, Q1) do { \
    bf0 = dq8(Q0, scp0, nzp0); bf1 = dq8(Q1, scp1, nzp1); \
} while (0)

#define MFMA8(AF) do { \
    __builtin_amdgcn_s_setprio(1); \
    _Pragma("unroll") for (int mb = 0; mb < 4; ++mb) { \
        acc[mb][0] = __builtin_amdgcn_mfma_f32_32x32x16_f16(AF[mb], bf0, acc[mb][0], 0, 0, 0); \
        acc[mb][1] = __builtin_amdgcn_mfma_f32_32x32x16_f16(AF[mb], bf1, acc[mb][1], 0, 0, 0); \
    } \
    __builtin_amdgcn_s_setprio(0); \
    SB(); \
} while (0)

#define CVT_S() do { \
    const float _s0 = __uint_as_float(sS0), _s1 = __uint_as_float(sS1); \
    const __half _h0 = __float2half_rn(_s0), _h1 = __float2half_rn(_s1); \
    scp0 = __half2(_h0, _h0); scp1 = __half2(_h1, _h1); \
    const __half _n0 = __float2half_rn(-_s0 * (float)((sZ0 >> sh4) & 15u)); \
    const __half _n1 = __float2half_rn(-_s1 * (float)((sZ1 >> sh4) & 15u)); \
    nzp0 = __half2(_n0, _n0); nzp1 = __half2(_n1, _n1); \
} while (0)

#define SWAP_A() do { unsigned char* _tp = aR; aR = aW; aW = _tp; } while (0)

// ---- fused GEMM: 256x256, 8 waves (2Mx4N), MFMA 32x32x16, B dequant-to-reg.
// Wave-tile 128x64 = 4 mblk x 2 nblk of 32x32. 4 k-steps (K=16) per 64-k tile,
// ks-granular ds prefetch (counted lgkmcnt), r15's counted-vmcnt ledger.
__global__ __launch_bounds__(512, 2)
void r17_gemm(const __half* __restrict__ xh,
              const int*   __restrict__ qweight,
              const int*   __restrict__ qzeros,
              const float* __restrict__ scales,
              const float* __restrict__ bias,
              float* __restrict__ out)
{
    __shared__ __align__(16) unsigned char A0s[ATB], A1s[ATB];   // 64 KB

    const int tid  = threadIdx.x;
    const int lane = tid & 63;
    const int wid  = tid >> 6;
    const int wr   = (wid >> 2) * 128;   // wave M offset (0,128)
    const int wc   = (wid & 3) * 64;     // wave N offset (0,64,128,192)

    int bid = blockIdx.x;                // XCD swizzle (688 = 8*86)
    const int cpx = gridDim.x >> 3;
    bid = (bid & 7) * cpx + (bid >> 3);
    const int bm0 = (bid / NT_N) * BM;
    const int bn0 = (bid % NT_N) * BN;

    const int lrow = lane & 31;          // 32x32 row/col within block
    const int hi   = lane >> 5;          // k-half selector
    const int colb = bn0 + wc + lrow;    // lane's base output column (nblk=0)
    const int sh4  = (colb & 7) * 4;
    const int aBase = hi * 4096 + (wr + lrow) * 16;

    const char* agp = (const char*)xh + ((size_t)(bm0 >> 8) * NKT) * ATB + tid * 16;

    // q row pointers: rows {0,2,4,6}+hi (advance 8 rows per tile)
    const int* qp0 = qweight + (size_t)(0 + hi) * N_DIM + colb;
    const int* qp1 = qweight + (size_t)(2 + hi) * N_DIM + colb;
    const int* qp2 = qweight + (size_t)(4 + hi) * N_DIM + colb;
    const int* qp3 = qweight + (size_t)(6 + hi) * N_DIM + colb;
    const float* sp = scales + (size_t)N_DIM + colb;          // group 1
    const int*   zp = qzeros + (size_t)NZ8 + (colb >> 3);     // group 1

    unsigned char *aR = A0s, *aW = A1s;

    f32x16 acc[4][2];
#pragma unroll
    for (int mb = 0; mb < 4; ++mb)
#pragma unroll
        for (int nb = 0; nb < 2; ++nb)
#pragma unroll
            for (int r = 0; r < 16; ++r) acc[mb][nb][r] = 0.f;

    f16x8 afA[4], afB[4], bf0, bf1;
    __half2 scp0, scp1, nzp0, nzp1;
    unsigned qa0, qa1, qa2, qa3, qa4, qa5, qa6, qa7;
    unsigned qb0, qb1, qb2, qb3, qb4, qb5, qb6, qb7;
    unsigned sS0, sS1, sZ0, sZ1;

    // ---- prologue: group-0 scales plain-loaded & retired before the ledger
    sS0 = __float_as_uint(scales[colb]);
    sS1 = __float_as_uint(scales[colb + 32]);
    sZ0 = (unsigned)qzeros[(colb >> 3)];
    sZ1 = (unsigned)qzeros[(colb >> 3) + 4];
    asm volatile("" : "+v"(sS0), "+v"(sS1), "+v"(sZ0), "+v"(sZ1));
    VMW(0);
    // ledger: qa(t0)[8], A(0)[4], qb(t1)[8], A(1)[4] -> 24 outstanding
    ISSUE_Q8(qa0, qa1, qa2, qa3, qa4, qa5, qa6, qa7);   // tile 0
    ISSUE_A(aR, 0);
    ISSUE_Q8(qb0, qb1, qb2, qb3, qb4, qb5, qb6, qb7);   // tile 1
    ISSUE_A(aW, 1);
    VMW(12);                     // retire qa[8]+A(0)[4]; leaves qb[8]+A(1)[4]
    BAR();
    FRAGS_KS(aR, 0, afA);        // tile 0, ks0

    // ---- main loop: u = 0..30, tiles (2u, 2u+1); issues for 2u+2, 2u+3
    for (int u = 0; u < 31; ++u) {
        CVT_S();                                 // group u (raw retired)
        // ===== even tile 2u =====
        FRAGS_KS(aR, 1, afB); DQ2(qa0, qa1); LGKMC(4); MFMA8(afA);
        FRAGS_KS(aR, 2, afA); DQ2(qa2, qa3); LGKMC(4); MFMA8(afB);
        FRAGS_KS(aR, 3, afB); DQ2(qa4, qa5); LGKMC(4); MFMA8(afA);
        DQ2(qa6, qa7);
        ISSUE_Q8(qa0, qa1, qa2, qa3, qa4, qa5, qa6, qa7);   // tile 2u+2
        ISSUE_SZ();                                          // group u+1
        LGKMC(0); MFMA8(afB);
        VMW(12);                 // retire qb(2u+1)[8]+A(2u+1)[4]
        BAR(); SB();
        SWAP_A();
        ISSUE_A(aW, 2 * u + 2);
        FRAGS_KS(aR, 0, afA);                    // next tile, ks0
        // ===== odd tile 2u+1 =====
        FRAGS_KS(aR, 1, afB); DQ2(qb0, qb1); LGKMC(4); MFMA8(afA);
        FRAGS_KS(aR, 2, afA); DQ2(qb2, qb3); LGKMC(4); MFMA8(afB);
        FRAGS_KS(aR, 3, afB); DQ2(qb4, qb5); LGKMC(4); MFMA8(afA);
        DQ2(qb6, qb7);
        ISSUE_Q8(qb0, qb1, qb2, qb3, qb4, qb5, qb6, qb7);   // tile 2u+3
        LGKMC(0); MFMA8(afB);
        VMW(8);                  // retire qa(2u+2)[8]+SZ[4]+A(2u+2)[4]
        BAR(); SB();
        SWAP_A();
        ISSUE_A(aW, 2 * u + 3);
        FRAGS_KS(aR, 0, afA);                    // next tile, ks0
    }

    // ---- tail: tiles 62, 63 (outstanding: qb(63)[8] + A(63)[4])
    CVT_S();                                     // group 31
    // tile 62
    FRAGS_KS(aR, 1, afB); DQ2(qa0, qa1); LGKMC(4); MFMA8(afA);
    FRAGS_KS(aR, 2, afA); DQ2(qa2, qa3); LGKMC(4); MFMA8(afB);
    FRAGS_KS(aR, 3, afB); DQ2(qa4, qa5); LGKMC(4); MFMA8(afA);
    DQ2(qa6, qa7); LGKMC(0); MFMA8(afB);
    VMW(0);                      // drain qb(63) + A(63)
    BAR(); SB();
    SWAP_A();
    FRAGS_KS(aR, 0, afA);
    // tile 63
    FRAGS_KS(aR, 1, afB); DQ2(qb0, qb1); LGKMC(4); MFMA8(afA);
    FRAGS_KS(aR, 2, afA); DQ2(qb2, qb3); LGKMC(4); MFMA8(afB);
    FRAGS_KS(aR, 3, afB); DQ2(qb4, qb5); LGKMC(4); MFMA8(afA);
    DQ2(qb6, qb7); LGKMC(0); MFMA8(afB);

    // ---- epilogue: 32x32 C/D layout (m74/m101): col=lane&31,
    // row = (r&3) + 8*(r>>2) + 4*hi
#pragma unroll
    for (int nb = 0; nb < 2; ++nb) {
        const int col = colb + nb * 32;
        const float bv = bias[col];
#pragma unroll
        for (int mb = 0; mb < 4; ++mb) {
            const int rb = bm0 + wr + mb * 32 + 4 * hi;
#pragma unroll
            for (int r = 0; r < 16; ++r) {
                const int row = rb + (r & 3) + 8 * (r >> 2);
                out[(size_t)row * N_DIM + col] = acc[mb][nb][r] + bv;
            }
        }
    }
}

// ---------------- fallback (ws too small): proven r8 kernel ----------------
typedef __bf16 bf16x8 __attribute__((ext_vector_type(8)));
typedef float  f32x4  __attribute__((ext_vector_type(4)));

__global__ __launch_bounds__(256, 2)
void r17_fb(const float* __restrict__ x,
            const int*   __restrict__ qweight,
            const int*   __restrict__ qzeros,
            const float* __restrict__ scales,
            const float* __restrict__ bias,
            float* __restrict__ out)
{
    __shared__ __align__(16) unsigned char Asm[128 * 64 * 2];
    __shared__ __align__(16) unsigned char Bsm[128 * 64 * 2];
    const int tid = threadIdx.x, lane = tid & 63, wv = tid >> 6;
    const int wr = (wv >> 1) * 64, wc = (wv & 1) * 64;
    int bid = blockIdx.x;
    const int cpx = gridDim.x >> 3;
    bid = (bid & 7) * cpx + (bid >> 3);
    const int bm0 = (bid / 86) * 128, bn0 = (bid % 86) * 128;
    const int ar = tid >> 4, ac4 = tid & 15;
    const float* xp = x + (size_t)(bm0 + ar) * K_DIM + ac4 * 4;
    unsigned char* aw = Asm + ar * 128 + ((ac4 * 8) ^ ((ar & 7) << 4));
    const int bnn = tid & 127, bk8q = tid >> 7, ngl = bn0 + bnn;
    const int* qwp = qweight + (size_t)bk8q * N_DIM + ngl;
    unsigned char* bw = Bsm + bnn * 128;
    const int bsw = bnn & 7;
    const int frow = lane & 15, kb8 = lane >> 4, fsw = frow & 7;
    f32x4 acc[4][4];
#pragma unroll
    for (int m = 0; m < 4; ++m)
#pragma unroll
        for (int n = 0; n < 4; ++n) acc[m][n] = (f32x4){0.f, 0.f, 0.f, 0.f};
    float sc = 0.f, nsz = 0.f;
    for (int kt = 0; kt < K_DIM / 64; ++kt) {
        const int k0 = kt * 64;
        if ((k0 & 127) == 0) {
            const int g = k0 >> 7;
            sc = scales[(size_t)g * N_DIM + ngl];
            const unsigned zq = (unsigned)qzeros[(size_t)g * NZ8 + (ngl >> 3)];
            nsz = -sc * (float)((zq >> ((ngl & 7) * 4)) & 15u);
        }
#pragma unroll
        for (int i = 0; i < 8; ++i) {
            const float4 v = *(const float4*)(xp + (size_t)i * 16 * K_DIM + k0);
            union { __bf16 h[4]; unsigned long long u; } p;
            p.h[0] = (__bf16)v.x; p.h[1] = (__bf16)v.y;
            p.h[2] = (__bf16)v.z; p.h[3] = (__bf16)v.w;
            *(unsigned long long*)(aw + i * 16 * 128) = p.u;
        }
#pragma unroll
        for (int i = 0; i < 4; ++i) {
            const int k8 = 2 * i + bk8q;
            const unsigned q = (unsigned)qwp[(size_t)(kt * 8 + 2 * i) * N_DIM];
            union { __bf16 h[8]; bf16x8 v8; } p;
#pragma unroll
            for (int j = 0; j < 8; ++j)
                p.h[j] = (__bf16)__builtin_fmaf(sc, (float)((q >> (4 * j)) & 15u), nsz);
            *(bf16x8*)(bw + ((k8 ^ bsw) << 4)) = p.v8;
        }
        __syncthreads();
#pragma unroll
        for (int kh = 0; kh < 2; ++kh) {
            const int ksl = (kh << 2) + kb8;
            bf16x8 a2[4], b2[4];
#pragma unroll
            for (int m = 0; m < 4; ++m)
                a2[m] = *(const bf16x8*)(Asm + (wr + m * 16 + frow) * 128 + ((ksl ^ fsw) << 4));
#pragma unroll
            for (int n = 0; n < 4; ++n)
                b2[n] = *(const bf16x8*)(Bsm + (wc + n * 16 + frow) * 128 + ((ksl ^ fsw) << 4));
#pragma unroll
            for (int m = 0; m < 4; ++m)
#pragma unroll
                for (int n = 0; n < 4; ++n)
                    acc[m][n] = __builtin_amdgcn_mfma_f32_16x16x32_bf16(a2[m], b2[n], acc[m][n], 0, 0, 0);
        }
        __syncthreads();
    }
    const int crow0 = (lane >> 4) << 2, ccol = lane & 15;
#pragma unroll
    for (int n = 0; n < 4; ++n) {
        const int col = bn0 + wc + n * 16 + ccol;
        const float bv = bias[col];
#pragma unroll
        for (int m = 0; m < 4; ++m) {
            const int row = bm0 + wr + m * 16 + crow0;
#pragma unroll
            for (int j = 0; j < 4; ++j)
                out[(size_t)(row + j) * N_DIM + col] = acc[m][n][j] + bv;
        }
    }
}

extern "C" void kernel_launch(void* const* d_in, const int* in_sizes, int n_in,
                              void* d_out, int out_size, void* d_ws, size_t ws_size,
                              hipStream_t stream)
{
    const float* x   = (const float*)d_in[0];
    const int*   qw  = (const int*)d_in[1];
    const int*   qz  = (const int*)d_in[2];
    const float* scl = (const float*)d_in[3];
    const float* bs  = (const float*)d_in[4];
    float* out = (float*)d_out;

    const int M = in_sizes[0] / K_DIM;               // 4096
    const size_t xh_bytes = (size_t)M * K_DIM * 2;   // 33.6 MB

    if (ws_size >= xh_bytes) {
        __half* xh = (__half*)d_ws;
        const int nchunks = M * K_DIM / 8;
        hipLaunchKernelGGL(r17_xcvt, dim3(2048), dim3(256), 0, stream, x, xh, nchunks);
        dim3 grid((M / BM) * NT_N);                  // 688
        hipLaunchKernelGGL(r17_gemm, grid, dim3(512), 0, stream,
                           xh, qw, qz, scl, bs, out);
    } else {
        dim3 grid((M / 128) * 86);                   // 2752
        hipLaunchKernelGGL(r17_fb, grid, dim3(256), 0, stream,
                           x, qw, qz, scl, bs, out);
    }
}